// Round 6
// baseline (561.318 us; speedup 1.0000x reference)
//
#include <hip/hip_runtime.h>
#include <math.h>

#define WDIM 512
#define HDIM 8
#define NPAIRS 32768          // 65536 rows / 2 rows per wave-iteration

// Native clang vector type — __builtin_nontemporal_{load,store} require it.
typedef float native_float4 __attribute__((ext_vector_type(4)));

// ---- DPP cross-lane (VALU pipe) ----
template<int CTRL, int ROWM>
__device__ __forceinline__ float dpp_mov(float oldv, float x) {
    return __int_as_float(__builtin_amdgcn_update_dpp(
        __float_as_int(oldv), __float_as_int(x), CTRL, ROWM, 0xF, false));
}

// Full-wave (64-lane) sum, broadcast via readlane(63). Order == R2/R5.
__device__ __forceinline__ float wave_sum(float x) {
    x += dpp_mov<0x121, 0xF>(0.f, x);   // row_ror:1
    x += dpp_mov<0x122, 0xF>(0.f, x);   // row_ror:2
    x += dpp_mov<0x124, 0xF>(0.f, x);   // row_ror:4
    x += dpp_mov<0x128, 0xF>(0.f, x);   // row_ror:8  -> row-of-16 sums
    x += dpp_mov<0x142, 0xA>(0.f, x);   // row_bcast15
    x += dpp_mov<0x143, 0xC>(0.f, x);   // row_bcast31 -> lane63 = total
    return __int_as_float(__builtin_amdgcn_readlane(__float_as_int(x), 63));
}

__device__ __forceinline__ float dot8(native_float4 a0, native_float4 a1,
                                      native_float4 b0, native_float4 b1) {
    float s = a0.x * b0.x;
    s = fmaf(a0.y, b0.y, s); s = fmaf(a0.z, b0.z, s); s = fmaf(a0.w, b0.w, s);
    s = fmaf(a1.x, b1.x, s); s = fmaf(a1.y, b1.y, s);
    s = fmaf(a1.z, b1.z, s); s = fmaf(a1.w, b1.w, s);
    return s;
}

// Order-isomorphic uint key for fp32: k(a) > k(b) <=> a > b (no ties created).
__device__ __forceinline__ unsigned mono_key(float y) {
    unsigned b = __float_as_uint(y);
    return b ^ (unsigned)(((int)b >> 31) | (int)0x80000000);
}

// LDS = exactly 32 KiB (W1 + W3t) -> 5 blocks/CU, 20 waves/CU.
// launch_bounds(256,5): VGPR cap ~102; measured need ~90 (no spill).
__global__ __launch_bounds__(256, 5)
void fused_mlp_topk(const float* __restrict__ x,
                    const float* __restrict__ W1,
                    const float* __restrict__ b1,
                    const float* __restrict__ W2,
                    const float* __restrict__ b2,
                    const float* __restrict__ W3,
                    const float* __restrict__ b3,
                    float* __restrict__ out)
{
    __shared__ __align__(16) float sW1[HDIM * WDIM];    // 16 KiB
    __shared__ __align__(16) float sW3t[HDIM * WDIM];   // 16 KiB

    const int tid = threadIdx.x;
    for (int i = tid; i < HDIM * WDIM; i += 256) sW1[i] = W1[i];
    for (int i = tid; i < HDIM * WDIM; i += 256) {
        int r = i >> 3, k = i & 7;          // W3 is (512,8) row-major
        sW3t[k * WDIM + r] = W3[i];
    }
    __syncthreads();

    const int lane = tid & 63;
    const int wave_id = blockIdx.x * 4 + (tid >> 6);
    const int n_waves = gridDim.x * 4;          // 5120 waves

    const native_float4* sW1v = reinterpret_cast<const native_float4*>(sW1);
    const native_float4* sW3v = reinterpret_cast<const native_float4*>(sW3t);

    // b3 fragments: loop-invariant -> hold in 8 VGPRs instead of LDS.
    const native_float4* b3v = reinterpret_cast<const native_float4*>(b3);
    const native_float4 b3a = b3v[lane];
    const native_float4 b3b = b3v[lane + 64];

    int pair = wave_id;                          // < 5120 < NPAIRS always
    const native_float4* xpa = reinterpret_cast<const native_float4*>(x + (size_t)pair * 2 * WDIM);
    native_float4 xa0 = __builtin_nontemporal_load(xpa + lane);
    native_float4 xa1 = __builtin_nontemporal_load(xpa + lane + 64);
    native_float4 xb0 = __builtin_nontemporal_load(xpa + lane + 128);
    native_float4 xb1 = __builtin_nontemporal_load(xpa + lane + 192);

    #pragma unroll 1
    while (pair < NPAIRS) {
        // -------- layer 1: 8 dots of 512 per row; LDS reads shared --------
        float pa[HDIM], pb[HDIM];
        #pragma unroll
        for (int j = 0; j < HDIM; ++j) {
            native_float4 w0 = sW1v[j * 128 + lane];
            native_float4 w1 = sW1v[j * 128 + lane + 64];
            pa[j] = dot8(xa0, xa1, w0, w1);
            pb[j] = dot8(xb0, xb1, w0, w1);
        }
        float h1a[HDIM], h1b[HDIM];
        #pragma unroll
        for (int j = 0; j < HDIM; ++j) {
            float sa = wave_sum(pa[j]) + b1[j];
            float sb = wave_sum(pb[j]) + b1[j];
            h1a[j] = sa > 0.f ? sa : 0.f;
            h1b[j] = sb > 0.f ? sb : 0.f;
        }

        // -------- layer 2: 8x8, wave-uniform (scalar W2/b2 loads) --------
        float h2a[HDIM], h2b[HDIM];
        #pragma unroll
        for (int j = 0; j < HDIM; ++j) {
            float va = b2[j], vb = b2[j];
            #pragma unroll
            for (int k = 0; k < HDIM; ++k) {
                const float w = W2[j * HDIM + k];
                va = fmaf(w, h1a[k], va);
                vb = fmaf(w, h1b[k], vb);
            }
            h2a[j] = va > 0.f ? va : 0.f;
            h2b[j] = vb > 0.f ? vb : 0.f;
        }

        // -------- layer 3: y = h2 . W3t[:, i] + b3; LDS reads shared ------
        native_float4 ya0 = b3a, ya1 = b3b;
        native_float4 yb0 = b3a, yb1 = b3b;
        #pragma unroll
        for (int k = 0; k < HDIM; ++k) {
            const float ha = h2a[k], hb = h2b[k];
            native_float4 w0 = sW3v[k * 128 + lane];
            native_float4 w1 = sW3v[k * 128 + lane + 64];
            ya0.x = fmaf(ha, w0.x, ya0.x); ya0.y = fmaf(ha, w0.y, ya0.y);
            ya0.z = fmaf(ha, w0.z, ya0.z); ya0.w = fmaf(ha, w0.w, ya0.w);
            ya1.x = fmaf(ha, w1.x, ya1.x); ya1.y = fmaf(ha, w1.y, ya1.y);
            ya1.z = fmaf(ha, w1.z, ya1.z); ya1.w = fmaf(ha, w1.w, ya1.w);
            yb0.x = fmaf(hb, w0.x, yb0.x); yb0.y = fmaf(hb, w0.y, yb0.y);
            yb0.z = fmaf(hb, w0.z, yb0.z); yb0.w = fmaf(hb, w0.w, yb0.w);
            yb1.x = fmaf(hb, w1.x, yb1.x); yb1.y = fmaf(hb, w1.y, yb1.y);
            yb1.z = fmaf(hb, w1.z, yb1.z); yb1.w = fmaf(hb, w1.w, yb1.w);
        }

        // -------- prefetch next pair's x (covered by selection) -----------
        const int npair = pair + n_waves;
        native_float4 nxa0, nxa1, nxb0, nxb1;
        if (npair < NPAIRS) {
            const native_float4* nxp = reinterpret_cast<const native_float4*>(x + (size_t)npair * 2 * WDIM);
            nxa0 = __builtin_nontemporal_load(nxp + lane);
            nxa1 = __builtin_nontemporal_load(nxp + lane + 64);
            nxb0 = __builtin_nontemporal_load(nxp + lane + 128);
            nxb1 = __builtin_nontemporal_load(nxp + lane + 192);
        }

        // -------- selection in y-space (softmax dropped: strictly monotone,
        // mask == {col0, col511} U top-14-by-y of cols 1..510; same radix
        // construction as the validated p-space version, rank 14) ----------
        unsigned ka[8], kb[8];
        ka[0] = mono_key(ya0.x); ka[1] = mono_key(ya0.y);
        ka[2] = mono_key(ya0.z); ka[3] = mono_key(ya0.w);
        ka[4] = mono_key(ya1.x); ka[5] = mono_key(ya1.y);
        ka[6] = mono_key(ya1.z); ka[7] = mono_key(ya1.w);
        kb[0] = mono_key(yb0.x); kb[1] = mono_key(yb0.y);
        kb[2] = mono_key(yb0.z); kb[3] = mono_key(yb0.w);
        kb[4] = mono_key(yb1.x); kb[5] = mono_key(yb1.y);
        kb[6] = mono_key(yb1.z); kb[7] = mono_key(yb1.w);
        // exclude forced cols from the rank-14 competition
        if (lane == 0)  { ka[0] = 0u; kb[0] = 0u; }   // col 0
        if (lane == 63) { ka[7] = 0u; kb[7] = 0u; }   // col 511

        unsigned Ua = 0u, Ub = 0u;
        for (int b = 31; b >= 0; --b) {
            const unsigned bit = 1u << b;
            const unsigned cua = Ua | bit;
            const unsigned cub = Ub | bit;
            int ca = 0, cb = 0;
            #pragma unroll
            for (int t = 0; t < 8; ++t) {
                ca += __popcll(__ballot(ka[t] > cua));
                cb += __popcll(__ballot(kb[t] > cub));
            }
            if (ca >= 14) Ua = cua;
            if (cb >= 14) Ub = cub;
        }
        // mask: k > U  (== k >= U+1 == y >= 14th-largest middle y)

        // -------- emit 0/1 masks (non-temporal streaming stores) ----------
        native_float4 r0, r1, q0, q1;
        r0.x = ka[0] > Ua ? 1.f : 0.f;  r0.y = ka[1] > Ua ? 1.f : 0.f;
        r0.z = ka[2] > Ua ? 1.f : 0.f;  r0.w = ka[3] > Ua ? 1.f : 0.f;
        r1.x = ka[4] > Ua ? 1.f : 0.f;  r1.y = ka[5] > Ua ? 1.f : 0.f;
        r1.z = ka[6] > Ua ? 1.f : 0.f;  r1.w = ka[7] > Ua ? 1.f : 0.f;
        q0.x = kb[0] > Ub ? 1.f : 0.f;  q0.y = kb[1] > Ub ? 1.f : 0.f;
        q0.z = kb[2] > Ub ? 1.f : 0.f;  q0.w = kb[3] > Ub ? 1.f : 0.f;
        q1.x = kb[4] > Ub ? 1.f : 0.f;  q1.y = kb[5] > Ub ? 1.f : 0.f;
        q1.z = kb[6] > Ub ? 1.f : 0.f;  q1.w = kb[7] > Ub ? 1.f : 0.f;
        if (lane == 0)  { r0.x = 1.f; q0.x = 1.f; }   // forced col 0
        if (lane == 63) { r1.w = 1.f; q1.w = 1.f; }   // forced col 511

        native_float4* oa = reinterpret_cast<native_float4*>(out + (size_t)pair * 2 * WDIM);
        __builtin_nontemporal_store(r0, oa + lane);
        __builtin_nontemporal_store(r1, oa + lane + 64);
        __builtin_nontemporal_store(q0, oa + lane + 128);
        __builtin_nontemporal_store(q1, oa + lane + 192);

        pair = npair;
        xa0 = nxa0; xa1 = nxa1; xb0 = nxb0; xb1 = nxb1;
    }
}

extern "C" void kernel_launch(void* const* d_in, const int* in_sizes, int n_in,
                              void* d_out, int out_size, void* d_ws, size_t ws_size,
                              hipStream_t stream) {
    const float* x  = (const float*)d_in[0];
    const float* W1 = (const float*)d_in[1];
    const float* b1 = (const float*)d_in[2];
    const float* W2 = (const float*)d_in[3];
    const float* b2 = (const float*)d_in[4];
    const float* W3 = (const float*)d_in[5];
    const float* b3 = (const float*)d_in[6];
    float* out = (float*)d_out;

    // 1280 blocks x 256 thr = 5120 waves, persistent over 32768 row-pairs.
    // 5 blocks/CU (LDS = exactly 32 KiB), 20 waves/CU.
    fused_mlp_topk<<<dim3(1280), dim3(256), 0, stream>>>(x, W1, b1, W2, b2, W3, b3, out);
}

// Round 7
// 514.149 us; speedup vs baseline: 1.0917x; 1.0917x over previous
//
#include <hip/hip_runtime.h>
#include <math.h>

#define WDIM 512
#define HDIM 8
#define NPAIRS 32768          // 65536 rows / 2 rows per wave-iteration

// Native clang vector type — __builtin_nontemporal_{load,store} require it.
typedef float native_float4 __attribute__((ext_vector_type(4)));

// ---- DPP cross-lane (VALU pipe) ----
template<int CTRL, int ROWM>
__device__ __forceinline__ float dpp_mov(float oldv, float x) {
    return __int_as_float(__builtin_amdgcn_update_dpp(
        __float_as_int(oldv), __float_as_int(x), CTRL, ROWM, 0xF, false));
}

// Full-wave (64-lane) sum, broadcast via readlane(63). Order == R2/R5/R6.
__device__ __forceinline__ float wave_sum(float x) {
    x += dpp_mov<0x121, 0xF>(0.f, x);   // row_ror:1
    x += dpp_mov<0x122, 0xF>(0.f, x);   // row_ror:2
    x += dpp_mov<0x124, 0xF>(0.f, x);   // row_ror:4
    x += dpp_mov<0x128, 0xF>(0.f, x);   // row_ror:8  -> row-of-16 sums
    x += dpp_mov<0x142, 0xA>(0.f, x);   // row_bcast15
    x += dpp_mov<0x143, 0xC>(0.f, x);   // row_bcast31 -> lane63 = total
    return __int_as_float(__builtin_amdgcn_readlane(__float_as_int(x), 63));
}

__device__ __forceinline__ float dot8(native_float4 a0, native_float4 a1,
                                      native_float4 b0, native_float4 b1) {
    float s = a0.x * b0.x;
    s = fmaf(a0.y, b0.y, s); s = fmaf(a0.z, b0.z, s); s = fmaf(a0.w, b0.w, s);
    s = fmaf(a1.x, b1.x, s); s = fmaf(a1.y, b1.y, s);
    s = fmaf(a1.z, b1.z, s); s = fmaf(a1.w, b1.w, s);
    return s;
}

// Order-isomorphic uint key for fp32: k(a) > k(b) <=> a > b (no ties created).
__device__ __forceinline__ unsigned mono_key(float y) {
    unsigned b = __float_as_uint(y);
    return b ^ (unsigned)(((int)b >> 31) | (int)0x80000000);
}

// PROVEN allocator config: launch_bounds(256,4) -> VGPR budget 128, compiler
// lands ~64-80, NO spills. (256,5) and (1024,8) both collapsed the allocator
// (48/32 VGPRs) and spilled ~500 MB of scratch traffic — never again.
// LDS = exactly 32 KiB -> hardware fits 5 blocks/CU (20 waves/CU) when
// actual VGPR use <= 96; residency comes from ACTUAL use, not the bound.
__global__ __launch_bounds__(256, 4)
void fused_mlp_topk(const float* __restrict__ x,
                    const float* __restrict__ W1,
                    const float* __restrict__ b1,
                    const float* __restrict__ W2,
                    const float* __restrict__ b2,
                    const float* __restrict__ W3,
                    const float* __restrict__ b3,
                    float* __restrict__ out)
{
    __shared__ __align__(16) float sW1[HDIM * WDIM];    // 16 KiB
    __shared__ __align__(16) float sW3t[HDIM * WDIM];   // 16 KiB

    const int tid = threadIdx.x;
    for (int i = tid; i < HDIM * WDIM; i += 256) sW1[i] = W1[i];
    for (int i = tid; i < HDIM * WDIM; i += 256) {
        int r = i >> 3, k = i & 7;          // W3 is (512,8) row-major
        sW3t[k * WDIM + r] = W3[i];
    }
    __syncthreads();

    const int lane = tid & 63;
    const int wave_id = blockIdx.x * 4 + (tid >> 6);
    const int n_waves = gridDim.x * 4;          // 5120 waves

    const native_float4* sW1v = reinterpret_cast<const native_float4*>(sW1);
    const native_float4* sW3v = reinterpret_cast<const native_float4*>(sW3t);

    // b3 fragments: loop-invariant -> 8 VGPRs instead of LDS.
    const native_float4* b3v = reinterpret_cast<const native_float4*>(b3);
    const native_float4 b3a = b3v[lane];
    const native_float4 b3b = b3v[lane + 64];

    int pair = wave_id;                          // < 5120 < NPAIRS always
    const native_float4* xpa = reinterpret_cast<const native_float4*>(x + (size_t)pair * 2 * WDIM);
    native_float4 xa0 = __builtin_nontemporal_load(xpa + lane);
    native_float4 xa1 = __builtin_nontemporal_load(xpa + lane + 64);
    native_float4 xb0 = __builtin_nontemporal_load(xpa + lane + 128);
    native_float4 xb1 = __builtin_nontemporal_load(xpa + lane + 192);

    #pragma unroll 1
    while (pair < NPAIRS) {
        // -------- layer 1: 8 dots of 512 per row; LDS reads shared --------
        float pa[HDIM], pb[HDIM];
        #pragma unroll
        for (int j = 0; j < HDIM; ++j) {
            native_float4 w0 = sW1v[j * 128 + lane];
            native_float4 w1 = sW1v[j * 128 + lane + 64];
            pa[j] = dot8(xa0, xa1, w0, w1);
            pb[j] = dot8(xb0, xb1, w0, w1);
        }
        float h1a[HDIM], h1b[HDIM];
        #pragma unroll
        for (int j = 0; j < HDIM; ++j) {
            float sa = wave_sum(pa[j]) + b1[j];
            float sb = wave_sum(pb[j]) + b1[j];
            h1a[j] = sa > 0.f ? sa : 0.f;
            h1b[j] = sb > 0.f ? sb : 0.f;
        }

        // -------- layer 2: 8x8, wave-uniform (scalar W2/b2 loads) --------
        float h2a[HDIM], h2b[HDIM];
        #pragma unroll
        for (int j = 0; j < HDIM; ++j) {
            float va = b2[j], vb = b2[j];
            #pragma unroll
            for (int k = 0; k < HDIM; ++k) {
                const float w = W2[j * HDIM + k];
                va = fmaf(w, h1a[k], va);
                vb = fmaf(w, h1b[k], vb);
            }
            h2a[j] = va > 0.f ? va : 0.f;
            h2b[j] = vb > 0.f ? vb : 0.f;
        }

        // -------- layer 3: y = h2 . W3t[:, i] + b3; LDS reads shared ------
        native_float4 ya0 = b3a, ya1 = b3b;
        native_float4 yb0 = b3a, yb1 = b3b;
        #pragma unroll
        for (int k = 0; k < HDIM; ++k) {
            const float ha = h2a[k], hb = h2b[k];
            native_float4 w0 = sW3v[k * 128 + lane];
            native_float4 w1 = sW3v[k * 128 + lane + 64];
            ya0.x = fmaf(ha, w0.x, ya0.x); ya0.y = fmaf(ha, w0.y, ya0.y);
            ya0.z = fmaf(ha, w0.z, ya0.z); ya0.w = fmaf(ha, w0.w, ya0.w);
            ya1.x = fmaf(ha, w1.x, ya1.x); ya1.y = fmaf(ha, w1.y, ya1.y);
            ya1.z = fmaf(ha, w1.z, ya1.z); ya1.w = fmaf(ha, w1.w, ya1.w);
            yb0.x = fmaf(hb, w0.x, yb0.x); yb0.y = fmaf(hb, w0.y, yb0.y);
            yb0.z = fmaf(hb, w0.z, yb0.z); yb0.w = fmaf(hb, w0.w, yb0.w);
            yb1.x = fmaf(hb, w1.x, yb1.x); yb1.y = fmaf(hb, w1.y, yb1.y);
            yb1.z = fmaf(hb, w1.z, yb1.z); yb1.w = fmaf(hb, w1.w, yb1.w);
        }

        // -------- prefetch next pair's x (covered by selection) -----------
        const int npair = pair + n_waves;
        native_float4 nxa0, nxa1, nxb0, nxb1;
        if (npair < NPAIRS) {
            const native_float4* nxp = reinterpret_cast<const native_float4*>(x + (size_t)npair * 2 * WDIM);
            nxa0 = __builtin_nontemporal_load(nxp + lane);
            nxa1 = __builtin_nontemporal_load(nxp + lane + 64);
            nxb0 = __builtin_nontemporal_load(nxp + lane + 128);
            nxb1 = __builtin_nontemporal_load(nxp + lane + 192);
        }

        // -------- selection in y-space (validated in R6, absmax 0.0):
        // softmax is strictly monotone, so mask == {col0,col511} U
        // top-14-by-y of cols 1..510; radix bit-search on monotone uint keys,
        // rank 14, duplicate semantics preserved. ------------------------
        unsigned ka[8], kb[8];
        ka[0] = mono_key(ya0.x); ka[1] = mono_key(ya0.y);
        ka[2] = mono_key(ya0.z); ka[3] = mono_key(ya0.w);
        ka[4] = mono_key(ya1.x); ka[5] = mono_key(ya1.y);
        ka[6] = mono_key(ya1.z); ka[7] = mono_key(ya1.w);
        kb[0] = mono_key(yb0.x); kb[1] = mono_key(yb0.y);
        kb[2] = mono_key(yb0.z); kb[3] = mono_key(yb0.w);
        kb[4] = mono_key(yb1.x); kb[5] = mono_key(yb1.y);
        kb[6] = mono_key(yb1.z); kb[7] = mono_key(yb1.w);
        // exclude forced cols from the rank-14 competition
        if (lane == 0)  { ka[0] = 0u; kb[0] = 0u; }   // col 0
        if (lane == 63) { ka[7] = 0u; kb[7] = 0u; }   // col 511

        unsigned Ua = 0u, Ub = 0u;
        for (int b = 31; b >= 0; --b) {
            const unsigned bit = 1u << b;
            const unsigned cua = Ua | bit;
            const unsigned cub = Ub | bit;
            int ca = 0, cb = 0;
            #pragma unroll
            for (int t = 0; t < 8; ++t) {
                ca += __popcll(__ballot(ka[t] > cua));
                cb += __popcll(__ballot(kb[t] > cub));
            }
            if (ca >= 14) Ua = cua;
            if (cb >= 14) Ub = cub;
        }
        // mask: k > U  (== y >= 14th-largest middle y)

        // -------- emit 0/1 masks (non-temporal streaming stores) ----------
        native_float4 r0, r1, q0, q1;
        r0.x = ka[0] > Ua ? 1.f : 0.f;  r0.y = ka[1] > Ua ? 1.f : 0.f;
        r0.z = ka[2] > Ua ? 1.f : 0.f;  r0.w = ka[3] > Ua ? 1.f : 0.f;
        r1.x = ka[4] > Ua ? 1.f : 0.f;  r1.y = ka[5] > Ua ? 1.f : 0.f;
        r1.z = ka[6] > Ua ? 1.f : 0.f;  r1.w = ka[7] > Ua ? 1.f : 0.f;
        q0.x = kb[0] > Ub ? 1.f : 0.f;  q0.y = kb[1] > Ub ? 1.f : 0.f;
        q0.z = kb[2] > Ub ? 1.f : 0.f;  q0.w = kb[3] > Ub ? 1.f : 0.f;
        q1.x = kb[4] > Ub ? 1.f : 0.f;  q1.y = kb[5] > Ub ? 1.f : 0.f;
        q1.z = kb[6] > Ub ? 1.f : 0.f;  q1.w = kb[7] > Ub ? 1.f : 0.f;
        if (lane == 0)  { r0.x = 1.f; q0.x = 1.f; }   // forced col 0
        if (lane == 63) { r1.w = 1.f; q1.w = 1.f; }   // forced col 511

        native_float4* oa = reinterpret_cast<native_float4*>(out + (size_t)pair * 2 * WDIM);
        __builtin_nontemporal_store(r0, oa + lane);
        __builtin_nontemporal_store(r1, oa + lane + 64);
        __builtin_nontemporal_store(q0, oa + lane + 128);
        __builtin_nontemporal_store(q1, oa + lane + 192);

        pair = npair;
        xa0 = nxa0; xa1 = nxa1; xb0 = nxb0; xb1 = nxb1;
    }
}

extern "C" void kernel_launch(void* const* d_in, const int* in_sizes, int n_in,
                              void* d_out, int out_size, void* d_ws, size_t ws_size,
                              hipStream_t stream) {
    const float* x  = (const float*)d_in[0];
    const float* W1 = (const float*)d_in[1];
    const float* b1 = (const float*)d_in[2];
    const float* W2 = (const float*)d_in[3];
    const float* b2 = (const float*)d_in[4];
    const float* W3 = (const float*)d_in[5];
    const float* b3 = (const float*)d_in[6];
    float* out = (float*)d_out;

    // 1280 blocks x 256 thr = 5120 waves over 32768 row-pairs (6-7 pairs/wave).
    // LDS = exactly 32 KiB -> 5 blocks/CU resident when VGPR <= 96.
    fused_mlp_topk<<<dim3(1280), dim3(256), 0, stream>>>(x, W1, b1, W2, b2, W3, b3, out);
}

// Round 8
// 416.478 us; speedup vs baseline: 1.3478x; 1.2345x over previous
//
#include <hip/hip_runtime.h>
#include <math.h>

#define WDIM 512
#define HDIM 8
#define NPAIRS 32768          // 65536 rows / 2 rows per wave-iteration

// Native clang vector type — __builtin_nontemporal_{load,store} require it.
typedef float native_float4 __attribute__((ext_vector_type(4)));

// ---- DPP cross-lane (VALU pipe) ----
template<int CTRL, int ROWM>
__device__ __forceinline__ float dpp_mov(float oldv, float x) {
    return __int_as_float(__builtin_amdgcn_update_dpp(
        __float_as_int(oldv), __float_as_int(x), CTRL, ROWM, 0xF, false));
}

// Full-wave (64-lane) sum, broadcast via readlane(63). Order == R2/R5/R6/R7.
__device__ __forceinline__ float wave_sum(float x) {
    x += dpp_mov<0x121, 0xF>(0.f, x);   // row_ror:1
    x += dpp_mov<0x122, 0xF>(0.f, x);   // row_ror:2
    x += dpp_mov<0x124, 0xF>(0.f, x);   // row_ror:4
    x += dpp_mov<0x128, 0xF>(0.f, x);   // row_ror:8  -> row-of-16 sums
    x += dpp_mov<0x142, 0xA>(0.f, x);   // row_bcast15
    x += dpp_mov<0x143, 0xC>(0.f, x);   // row_bcast31 -> lane63 = total
    return __int_as_float(__builtin_amdgcn_readlane(__float_as_int(x), 63));
}

__device__ __forceinline__ float dot8(native_float4 a0, native_float4 a1,
                                      native_float4 b0, native_float4 b1) {
    float s = a0.x * b0.x;
    s = fmaf(a0.y, b0.y, s); s = fmaf(a0.z, b0.z, s); s = fmaf(a0.w, b0.w, s);
    s = fmaf(a1.x, b1.x, s); s = fmaf(a1.y, b1.y, s);
    s = fmaf(a1.z, b1.z, s); s = fmaf(a1.w, b1.w, s);
    return s;
}

// Order-isomorphic uint key for fp32: k(a) > k(b) <=> a > b (no ties created).
__device__ __forceinline__ unsigned mono_key(float y) {
    unsigned b = __float_as_uint(y);
    return b ^ (unsigned)(((int)b >> 31) | (int)0x80000000);
}

// PROVEN schedule (R5): 1024 blocks x 256 thr, launch_bounds(256,4) -> VGPR
// budget 128, compiler lands 64, NO spills. 4 blocks/CU guaranteed (32 KiB
// LDS), zero straggler round, exactly 8 pairs/wave uniform.
// Lessons burned in: (256,5)/(1024,8) collapse the allocator and spill
// (~500 MB scratch traffic); grid > resident capacity creates a 1-block/CU
// straggler round that doubled R7's duration.
__global__ __launch_bounds__(256, 4)
void fused_mlp_topk(const float* __restrict__ x,
                    const float* __restrict__ W1,
                    const float* __restrict__ b1,
                    const float* __restrict__ W2,
                    const float* __restrict__ b2,
                    const float* __restrict__ W3,
                    const float* __restrict__ b3,
                    float* __restrict__ out)
{
    __shared__ __align__(16) float sW1[HDIM * WDIM];    // 16 KiB
    __shared__ __align__(16) float sW3t[HDIM * WDIM];   // 16 KiB

    const int tid = threadIdx.x;
    for (int i = tid; i < HDIM * WDIM; i += 256) sW1[i] = W1[i];
    for (int i = tid; i < HDIM * WDIM; i += 256) {
        int r = i >> 3, k = i & 7;          // W3 is (512,8) row-major
        sW3t[k * WDIM + r] = W3[i];
    }
    __syncthreads();

    const int lane = tid & 63;
    const int wave_id = blockIdx.x * 4 + (tid >> 6);   // 4096 waves

    const native_float4* sW1v = reinterpret_cast<const native_float4*>(sW1);
    const native_float4* sW3v = reinterpret_cast<const native_float4*>(sW3t);

    // b3 fragments: loop-invariant -> 8 VGPRs instead of LDS.
    const native_float4* b3v = reinterpret_cast<const native_float4*>(b3);
    const native_float4 b3a = b3v[lane];
    const native_float4 b3b = b3v[lane + 64];

    int pair = wave_id;
    const native_float4* xpa = reinterpret_cast<const native_float4*>(x + (size_t)pair * 2 * WDIM);
    native_float4 xa0 = __builtin_nontemporal_load(xpa + lane);
    native_float4 xa1 = __builtin_nontemporal_load(xpa + lane + 64);
    native_float4 xb0 = __builtin_nontemporal_load(xpa + lane + 128);
    native_float4 xb1 = __builtin_nontemporal_load(xpa + lane + 192);

    #pragma unroll 1
    for (int it = 0; it < 8; ++it) {        // 4096 waves * 8 iters = 32768 pairs
        // -------- layer 1: 8 dots of 512 per row; LDS reads shared --------
        float pa[HDIM], pb[HDIM];
        #pragma unroll
        for (int j = 0; j < HDIM; ++j) {
            native_float4 w0 = sW1v[j * 128 + lane];
            native_float4 w1 = sW1v[j * 128 + lane + 64];
            pa[j] = dot8(xa0, xa1, w0, w1);
            pb[j] = dot8(xb0, xb1, w0, w1);
        }
        float h1a[HDIM], h1b[HDIM];
        #pragma unroll
        for (int j = 0; j < HDIM; ++j) {
            float sa = wave_sum(pa[j]) + b1[j];
            float sb = wave_sum(pb[j]) + b1[j];
            h1a[j] = sa > 0.f ? sa : 0.f;
            h1b[j] = sb > 0.f ? sb : 0.f;
        }

        // -------- layer 2: 8x8, wave-uniform (scalar W2/b2 loads) --------
        float h2a[HDIM], h2b[HDIM];
        #pragma unroll
        for (int j = 0; j < HDIM; ++j) {
            float va = b2[j], vb = b2[j];
            #pragma unroll
            for (int k = 0; k < HDIM; ++k) {
                const float w = W2[j * HDIM + k];
                va = fmaf(w, h1a[k], va);
                vb = fmaf(w, h1b[k], vb);
            }
            h2a[j] = va > 0.f ? va : 0.f;
            h2b[j] = vb > 0.f ? vb : 0.f;
        }

        // -------- layer 3: y = h2 . W3t[:, i] + b3; LDS reads shared ------
        native_float4 ya0 = b3a, ya1 = b3b;
        native_float4 yb0 = b3a, yb1 = b3b;
        #pragma unroll
        for (int k = 0; k < HDIM; ++k) {
            const float ha = h2a[k], hb = h2b[k];
            native_float4 w0 = sW3v[k * 128 + lane];
            native_float4 w1 = sW3v[k * 128 + lane + 64];
            ya0.x = fmaf(ha, w0.x, ya0.x); ya0.y = fmaf(ha, w0.y, ya0.y);
            ya0.z = fmaf(ha, w0.z, ya0.z); ya0.w = fmaf(ha, w0.w, ya0.w);
            ya1.x = fmaf(ha, w1.x, ya1.x); ya1.y = fmaf(ha, w1.y, ya1.y);
            ya1.z = fmaf(ha, w1.z, ya1.z); ya1.w = fmaf(ha, w1.w, ya1.w);
            yb0.x = fmaf(hb, w0.x, yb0.x); yb0.y = fmaf(hb, w0.y, yb0.y);
            yb0.z = fmaf(hb, w0.z, yb0.z); yb0.w = fmaf(hb, w0.w, yb0.w);
            yb1.x = fmaf(hb, w1.x, yb1.x); yb1.y = fmaf(hb, w1.y, yb1.y);
            yb1.z = fmaf(hb, w1.z, yb1.z); yb1.w = fmaf(hb, w1.w, yb1.w);
        }

        // -------- prefetch next pair's x (covered by selection) -----------
        const int npair = pair + 4096;
        native_float4 nxa0, nxa1, nxb0, nxb1;
        if (it < 7) {
            const native_float4* nxp = reinterpret_cast<const native_float4*>(x + (size_t)npair * 2 * WDIM);
            nxa0 = __builtin_nontemporal_load(nxp + lane);
            nxa1 = __builtin_nontemporal_load(nxp + lane + 64);
            nxb0 = __builtin_nontemporal_load(nxp + lane + 128);
            nxb1 = __builtin_nontemporal_load(nxp + lane + 192);
        }

        // -------- selection in y-space (validated R6/R7, absmax 0.0):
        // softmax strictly monotone => mask == {col0,col511} U top-14-by-y of
        // cols 1..510; radix bit-search on monotone uint keys, rank 14. ----
        unsigned ka[8], kb[8];
        ka[0] = mono_key(ya0.x); ka[1] = mono_key(ya0.y);
        ka[2] = mono_key(ya0.z); ka[3] = mono_key(ya0.w);
        ka[4] = mono_key(ya1.x); ka[5] = mono_key(ya1.y);
        ka[6] = mono_key(ya1.z); ka[7] = mono_key(ya1.w);
        kb[0] = mono_key(yb0.x); kb[1] = mono_key(yb0.y);
        kb[2] = mono_key(yb0.z); kb[3] = mono_key(yb0.w);
        kb[4] = mono_key(yb1.x); kb[5] = mono_key(yb1.y);
        kb[6] = mono_key(yb1.z); kb[7] = mono_key(yb1.w);
        // exclude forced cols from the rank-14 competition
        if (lane == 0)  { ka[0] = 0u; kb[0] = 0u; }   // col 0
        if (lane == 63) { ka[7] = 0u; kb[7] = 0u; }   // col 511

        unsigned Ua = 0u, Ub = 0u;
        for (int b = 31; b >= 0; --b) {
            const unsigned bit = 1u << b;
            const unsigned cua = Ua | bit;
            const unsigned cub = Ub | bit;
            int ca = 0, cb = 0;
            #pragma unroll
            for (int t = 0; t < 8; ++t) {
                ca += __popcll(__ballot(ka[t] > cua));
                cb += __popcll(__ballot(kb[t] > cub));
            }
            if (ca >= 14) Ua = cua;
            if (cb >= 14) Ub = cub;
        }
        // mask: k > U  (== y >= 14th-largest middle y)

        // -------- emit 0/1 masks (non-temporal streaming stores) ----------
        native_float4 r0, r1, q0, q1;
        r0.x = ka[0] > Ua ? 1.f : 0.f;  r0.y = ka[1] > Ua ? 1.f : 0.f;
        r0.z = ka[2] > Ua ? 1.f : 0.f;  r0.w = ka[3] > Ua ? 1.f : 0.f;
        r1.x = ka[4] > Ua ? 1.f : 0.f;  r1.y = ka[5] > Ua ? 1.f : 0.f;
        r1.z = ka[6] > Ua ? 1.f : 0.f;  r1.w = ka[7] > Ua ? 1.f : 0.f;
        q0.x = kb[0] > Ub ? 1.f : 0.f;  q0.y = kb[1] > Ub ? 1.f : 0.f;
        q0.z = kb[2] > Ub ? 1.f : 0.f;  q0.w = kb[3] > Ub ? 1.f : 0.f;
        q1.x = kb[4] > Ub ? 1.f : 0.f;  q1.y = kb[5] > Ub ? 1.f : 0.f;
        q1.z = kb[6] > Ub ? 1.f : 0.f;  q1.w = kb[7] > Ub ? 1.f : 0.f;
        if (lane == 0)  { r0.x = 1.f; q0.x = 1.f; }   // forced col 0
        if (lane == 63) { r1.w = 1.f; q1.w = 1.f; }   // forced col 511

        native_float4* oa = reinterpret_cast<native_float4*>(out + (size_t)pair * 2 * WDIM);
        __builtin_nontemporal_store(r0, oa + lane);
        __builtin_nontemporal_store(r1, oa + lane + 64);
        __builtin_nontemporal_store(q0, oa + lane + 128);
        __builtin_nontemporal_store(q1, oa + lane + 192);

        pair = npair;
        xa0 = nxa0; xa1 = nxa1; xb0 = nxb0; xb1 = nxb1;
    }
}

extern "C" void kernel_launch(void* const* d_in, const int* in_sizes, int n_in,
                              void* d_out, int out_size, void* d_ws, size_t ws_size,
                              hipStream_t stream) {
    const float* x  = (const float*)d_in[0];
    const float* W1 = (const float*)d_in[1];
    const float* b1 = (const float*)d_in[2];
    const float* W2 = (const float*)d_in[3];
    const float* b2 = (const float*)d_in[4];
    const float* W3 = (const float*)d_in[5];
    const float* b3 = (const float*)d_in[6];
    float* out = (float*)d_out;

    // 1024 blocks x 256 thr = 4096 waves; exactly 8 pairs/wave (zero tail).
    // 4 blocks/CU guaranteed (32 KiB LDS), 16 waves/CU.
    fused_mlp_topk<<<dim3(1024), dim3(256), 0, stream>>>(x, W1, b1, W2, b2, W3, b3, out);
}